// Round 3
// baseline (713.767 us; speedup 1.0000x reference)
//
#include <hip/hip_runtime.h>
#include <hip/hip_bf16.h>
#include <stdint.h>

// Problem: LuongConcatAttention  (additive attention)
//   dec (32,1024); enc (32,2048,1024); W_a (1024,2048); v (1024)  [dtype probed at runtime]
//   out alpha (32,2048) = softmax_s( sum_e tanh(decproj[b,e]+encproj[b,s,e]) * v[e] )
// Round 3: runtime dtype probe (fp32 vs bf16) — persistent NaN across two staging
// schemes points to fp32 inputs being misread as bf16 (low-mantissa halves alias
// to bf16 NaN patterns). All compute stays bf16-MFMA (error << 6.3e-5 threshold).

typedef __bf16 bf16x8 __attribute__((ext_vector_type(8)));
typedef float floatx4 __attribute__((ext_vector_type(4)));

#define M_TOT 65536
#define D_DIM 1024
#define WA_LD 2048
#define S_DIM 2048

__device__ __forceinline__ float bflo(unsigned int u) { return __uint_as_float(u << 16); }
__device__ __forceinline__ float bfhi(unsigned int u) { return __uint_as_float(u & 0xffff0000u); }
__device__ __forceinline__ float bf2f(unsigned short u) { return __uint_as_float(((unsigned int)u) << 16); }
__device__ __forceinline__ unsigned short f2bf(float f) {
    unsigned int u = __float_as_uint(f);
    u += 0x7fffu + ((u >> 16) & 1u);   // RNE (inputs guaranteed non-NaN)
    return (unsigned short)(u >> 16);
}
__device__ __forceinline__ unsigned int pack2(float a, float b) {
    return (unsigned int)f2bf(a) | ((unsigned int)f2bf(b) << 16);
}

// ---------------- kernel 0: dtype probe ----------------
// v has 1024 elements ~ N(0,1)/32. If bf16: every ushort's exponent field is in the
// small-number range -> cnt ~= 64. If fp32: only the 32 high-halves are -> cnt ~= 34.
__global__ void probe_kernel(const unsigned short* __restrict__ vraw, int* __restrict__ flag) {
    if (threadIdx.x == 0 && blockIdx.x == 0) {
        int cnt = 0;
        for (int i = 0; i < 64; ++i) {
            unsigned int ef = (vraw[i] >> 7) & 0xFFu;   // bf16 biased-exponent field
            cnt += (ef >= 0x66u && ef <= 0x7Du) ? 1 : 0; // |x| in [2^-25, 2^-2]
        }
        *flag = (cnt >= 48) ? 1 : 0;   // 1 = bf16 inputs, 0 = fp32 inputs
    }
}

// ---------------- kernel 1: dec_proj[b][e] = sum_k dec[b,k] * W_a[e,k] ----------------
__global__ __launch_bounds__(256) void decproj_kernel(
    const void* __restrict__ dec_raw,
    const void* __restrict__ Wa_raw,
    const int* __restrict__ flag,
    float* __restrict__ dp)
{
    const int isbf = *flag;
    const int b = blockIdx.y;
    const int e = blockIdx.x * 256 + threadIdx.x;
    __shared__ float s_d[1024];
    if (isbf) {
        const unsigned short* dec = (const unsigned short*)dec_raw;
        for (int t = threadIdx.x; t < 1024; t += 256)
            s_d[t] = bf2f(dec[b * 1024 + t]);
    } else {
        const float* dec = (const float*)dec_raw;
        for (int t = threadIdx.x; t < 1024; t += 256)
            s_d[t] = dec[b * 1024 + t];
    }
    __syncthreads();
    float sum = 0.f;
    if (isbf) {
        const unsigned short* wrow = (const unsigned short*)Wa_raw + (size_t)e * WA_LD; // Wd
        for (int k = 0; k < 1024; k += 8) {
            uint4 w = *(const uint4*)(wrow + k);
            sum += bflo(w.x) * s_d[k + 0] + bfhi(w.x) * s_d[k + 1]
                 + bflo(w.y) * s_d[k + 2] + bfhi(w.y) * s_d[k + 3]
                 + bflo(w.z) * s_d[k + 4] + bfhi(w.z) * s_d[k + 5]
                 + bflo(w.w) * s_d[k + 6] + bfhi(w.w) * s_d[k + 7];
        }
    } else {
        const float* wrow = (const float*)Wa_raw + (size_t)e * WA_LD;
        for (int k = 0; k < 1024; k += 4) {
            float4 w = *(const float4*)(wrow + k);
            sum += w.x * s_d[k] + w.y * s_d[k + 1] + w.z * s_d[k + 2] + w.w * s_d[k + 3];
        }
    }
    dp[b * 1024 + e] = sum;
}

// ---------------- kernel 2: fused GEMM (enc @ We^T) + tanh + v-dot -> partial scores ----
// grid (8, 512) block 256. Tile: BM=128 BN=128 BK=32. Register staging.
__global__ __launch_bounds__(256) void fused_gemm_kernel(
    const void* __restrict__ enc_raw,    // [65536,1024]
    const void* __restrict__ Wa_raw,     // [1024,2048]
    const void* __restrict__ v_raw,      // [1024]
    const float* __restrict__ dp,        // [32,1024]
    const int* __restrict__ flag,
    float* __restrict__ partial)         // [8][65536]
{
    __shared__ unsigned short As[128 * 32];
    __shared__ unsigned short Bs[128 * 32];
    __shared__ float s_dec[128];
    __shared__ float s_v[128];
    __shared__ float s_score[128];

    const int isbf = *flag;
    const int tid  = threadIdx.x;
    const int lane = tid & 63;
    const int wave = tid >> 6;
    const int wm   = wave >> 1;   // 0..1
    const int wn   = wave & 1;    // 0..1

    const int flat    = blockIdx.y * 8 + blockIdx.x;
    const int n_block = (flat >> 3) & 7;
    const int m_block = (flat & 7) | ((flat >> 6) << 3);
    const int b_idx   = m_block >> 4;            // 2048/128 = 16 m-tiles per batch row

    if (tid < 128) {
        s_dec[tid] = dp[b_idx * 1024 + n_block * 128 + tid];
        s_v[tid]   = isbf ? bf2f(((const unsigned short*)v_raw)[n_block * 128 + tid])
                          : ((const float*)v_raw)[n_block * 128 + tid];
    }

    const int r0 = tid >> 2;          // rows r0 and r0+64
    const int kk = (tid & 3) * 8;     // k-offset within 32-wide tile
    const int r16 = lane & 15;
    const int q   = lane >> 4;

    floatx4 acc[4][4] = {};

    if (isbf) {
        const unsigned short* A_base = (const unsigned short*)enc_raw + (size_t)m_block * 128 * D_DIM;
        const unsigned short* B_base = (const unsigned short*)Wa_raw + (size_t)n_block * 128 * WA_LD + D_DIM;
        for (int k0 = 0; k0 < 1024; k0 += 32) {
            uint4 a0 = *(const uint4*)(A_base + (size_t)r0        * D_DIM + k0 + kk);
            uint4 a1 = *(const uint4*)(A_base + (size_t)(r0 + 64) * D_DIM + k0 + kk);
            uint4 b0 = *(const uint4*)(B_base + (size_t)r0        * WA_LD + k0 + kk);
            uint4 b1 = *(const uint4*)(B_base + (size_t)(r0 + 64) * WA_LD + k0 + kk);
            __syncthreads();
            *(uint4*)&As[r0        * 32 + kk] = a0;
            *(uint4*)&As[(r0 + 64) * 32 + kk] = a1;
            *(uint4*)&Bs[r0        * 32 + kk] = b0;
            *(uint4*)&Bs[(r0 + 64) * 32 + kk] = b1;
            __syncthreads();
            bf16x8 af[4], bfr[4];
            #pragma unroll
            for (int i = 0; i < 4; ++i)
                af[i] = *(const bf16x8*)&As[(wm * 64 + i * 16 + r16) * 32 + q * 8];
            #pragma unroll
            for (int j = 0; j < 4; ++j)
                bfr[j] = *(const bf16x8*)&Bs[(wn * 64 + j * 16 + r16) * 32 + q * 8];
            #pragma unroll
            for (int i = 0; i < 4; ++i)
                #pragma unroll
                for (int j = 0; j < 4; ++j)
                    acc[i][j] = __builtin_amdgcn_mfma_f32_16x16x32_bf16(af[i], bfr[j], acc[i][j], 0, 0, 0);
        }
    } else {
        const float* A_base = (const float*)enc_raw + (size_t)m_block * 128 * D_DIM;
        const float* B_base = (const float*)Wa_raw + (size_t)n_block * 128 * WA_LD + D_DIM;
        for (int k0 = 0; k0 < 1024; k0 += 32) {
            float4 a0l = *(const float4*)(A_base + (size_t)r0        * D_DIM + k0 + kk);
            float4 a0h = *(const float4*)(A_base + (size_t)r0        * D_DIM + k0 + kk + 4);
            float4 a1l = *(const float4*)(A_base + (size_t)(r0 + 64) * D_DIM + k0 + kk);
            float4 a1h = *(const float4*)(A_base + (size_t)(r0 + 64) * D_DIM + k0 + kk + 4);
            float4 b0l = *(const float4*)(B_base + (size_t)r0        * WA_LD + k0 + kk);
            float4 b0h = *(const float4*)(B_base + (size_t)r0        * WA_LD + k0 + kk + 4);
            float4 b1l = *(const float4*)(B_base + (size_t)(r0 + 64) * WA_LD + k0 + kk);
            float4 b1h = *(const float4*)(B_base + (size_t)(r0 + 64) * WA_LD + k0 + kk + 4);
            uint4 pa0 = { pack2(a0l.x, a0l.y), pack2(a0l.z, a0l.w), pack2(a0h.x, a0h.y), pack2(a0h.z, a0h.w) };
            uint4 pa1 = { pack2(a1l.x, a1l.y), pack2(a1l.z, a1l.w), pack2(a1h.x, a1h.y), pack2(a1h.z, a1h.w) };
            uint4 pb0 = { pack2(b0l.x, b0l.y), pack2(b0l.z, b0l.w), pack2(b0h.x, b0h.y), pack2(b0h.z, b0h.w) };
            uint4 pb1 = { pack2(b1l.x, b1l.y), pack2(b1l.z, b1l.w), pack2(b1h.x, b1h.y), pack2(b1h.z, b1h.w) };
            __syncthreads();
            *(uint4*)&As[r0        * 32 + kk] = pa0;
            *(uint4*)&As[(r0 + 64) * 32 + kk] = pa1;
            *(uint4*)&Bs[r0        * 32 + kk] = pb0;
            *(uint4*)&Bs[(r0 + 64) * 32 + kk] = pb1;
            __syncthreads();
            bf16x8 af[4], bfr[4];
            #pragma unroll
            for (int i = 0; i < 4; ++i)
                af[i] = *(const bf16x8*)&As[(wm * 64 + i * 16 + r16) * 32 + q * 8];
            #pragma unroll
            for (int j = 0; j < 4; ++j)
                bfr[j] = *(const bf16x8*)&Bs[(wn * 64 + j * 16 + r16) * 32 + q * 8];
            #pragma unroll
            for (int i = 0; i < 4; ++i)
                #pragma unroll
                for (int j = 0; j < 4; ++j)
                    acc[i][j] = __builtin_amdgcn_mfma_f32_16x16x32_bf16(af[i], bfr[j], acc[i][j], 0, 0, 0);
        }
    }

    // ---- epilogue: h = tanh(acc + dec), p[m] += h * v[n]; reduce over n ----
    float p[4][4] = {};
    #pragma unroll
    for (int j = 0; j < 4; ++j) {
        const int nl = wn * 64 + j * 16 + r16;    // C/D: col = lane&15 -> n
        const float dd = s_dec[nl];
        const float vv = s_v[nl];
        #pragma unroll
        for (int i = 0; i < 4; ++i) {
            #pragma unroll
            for (int r = 0; r < 4; ++r) {         // C/D: row = q*4+r -> m
                float x = acc[i][j][r] + dd;
                if (!(x > -8.f)) x = -8.f;        // NaN-proof clamp
                if (x > 8.f)     x = 8.f;
                float e2 = __expf(2.f * x);
                float h  = 1.f - 2.f * __builtin_amdgcn_rcpf(e2 + 1.f);
                p[i][r] += h * vv;
            }
        }
    }
    #pragma unroll
    for (int msk = 1; msk < 16; msk <<= 1) {
        #pragma unroll
        for (int i = 0; i < 4; ++i)
            #pragma unroll
            for (int r = 0; r < 4; ++r)
                p[i][r] += __shfl_xor(p[i][r], msk, 64);
    }
    __syncthreads();
    if (wn == 0 && r16 == 0) {
        #pragma unroll
        for (int i = 0; i < 4; ++i)
            #pragma unroll
            for (int r = 0; r < 4; ++r)
                s_score[wm * 64 + i * 16 + q * 4 + r] = p[i][r];
    }
    __syncthreads();
    if (wn == 1 && r16 == 0) {
        #pragma unroll
        for (int i = 0; i < 4; ++i)
            #pragma unroll
            for (int r = 0; r < 4; ++r)
                s_score[wm * 64 + i * 16 + q * 4 + r] += p[i][r];
    }
    __syncthreads();
    if (tid < 128)
        partial[(size_t)n_block * M_TOT + m_block * 128 + tid] = s_score[tid];
}

// ---------------- kernel 3: softmax over s per batch row ----------------
__global__ __launch_bounds__(256) void softmax_kernel(
    const float* __restrict__ partial,   // [8][65536]
    const int* __restrict__ flag,
    void* __restrict__ out_raw)          // [32][2048]
{
    const int isbf = *flag;
    const int b = blockIdx.x;
    const int tid = threadIdx.x;
    __shared__ float wmax[4], wsum[4];

    float sc[8];
    float mx = -1e30f;
    #pragma unroll
    for (int ii = 0; ii < 8; ++ii) {
        const int s = tid + ii * 256;
        float sum = 0.f;
        #pragma unroll
        for (int pp = 0; pp < 8; ++pp)
            sum += partial[(size_t)pp * M_TOT + b * S_DIM + s];
        sc[ii] = sum;
        mx = fmaxf(mx, sum);
    }
    #pragma unroll
    for (int msk = 1; msk < 64; msk <<= 1) mx = fmaxf(mx, __shfl_xor(mx, msk, 64));
    if ((tid & 63) == 0) wmax[tid >> 6] = mx;
    __syncthreads();
    mx = fmaxf(fmaxf(wmax[0], wmax[1]), fmaxf(wmax[2], wmax[3]));

    float ex[8];
    float tot = 0.f;
    #pragma unroll
    for (int ii = 0; ii < 8; ++ii) { ex[ii] = __expf(sc[ii] - mx); tot += ex[ii]; }
    #pragma unroll
    for (int msk = 1; msk < 64; msk <<= 1) tot += __shfl_xor(tot, msk, 64);
    if ((tid & 63) == 0) wsum[tid >> 6] = tot;
    __syncthreads();
    tot = wsum[0] + wsum[1] + wsum[2] + wsum[3];
    const float inv = 1.f / tot;
    if (isbf) {
        unsigned short* out = (unsigned short*)out_raw;
        #pragma unroll
        for (int ii = 0; ii < 8; ++ii)
            out[b * S_DIM + tid + ii * 256] = f2bf(ex[ii] * inv);
    } else {
        float* out = (float*)out_raw;
        #pragma unroll
        for (int ii = 0; ii < 8; ++ii)
            out[b * S_DIM + tid + ii * 256] = ex[ii] * inv;
    }
}

extern "C" void kernel_launch(void* const* d_in, const int* in_sizes, int n_in,
                              void* d_out, int out_size, void* d_ws, size_t ws_size,
                              hipStream_t stream) {
    (void)in_sizes; (void)n_in; (void)out_size; (void)ws_size;
    const void* dec = d_in[0];
    const void* enc = d_in[1];
    const void* Wa  = d_in[2];
    const void* v   = d_in[3];

    int*   flagp   = (int*)d_ws;                      // 64 B reserved
    float* dp      = (float*)((char*)d_ws + 64);      // 32*1024 floats = 128 KB
    float* partial = dp + 32 * 1024;                  // 8*65536 floats = 2 MB

    probe_kernel<<<1, 64, 0, stream>>>((const unsigned short*)v, flagp);
    decproj_kernel<<<dim3(4, 32), 256, 0, stream>>>(dec, Wa, flagp, dp);
    fused_gemm_kernel<<<dim3(8, 512), 256, 0, stream>>>(enc, Wa, v, dp, flagp, partial);
    softmax_kernel<<<32, 256, 0, stream>>>(partial, flagp, d_out);
}

// Round 4
// 589.382 us; speedup vs baseline: 1.2110x; 1.2110x over previous
//
#include <hip/hip_runtime.h>
#include <hip/hip_bf16.h>
#include <stdint.h>

// Problem: LuongConcatAttention (additive attention), fp32 inputs (probed R3).
//   dec (32,1024) f32; enc (32,2048,1024) f32; W_a (1024,2048) f32; v (1024) f32
//   out alpha (32,2048) f32 = softmax_s( sum_e tanh(decproj[b,e]+encproj[b,s,e]) * v[e] )
// Main cost: enc@We^T GEMM  M=65536 N=1024 K=1024 -> 137 GFLOP via bf16 MFMA
// (bf16-RNE conversion error measured at 1.5e-5 absmax, threshold 6.3e-5).
// Round 4: hardcode fp32; HW v_cvt_pk_bf16_f32 pack; coalesced wave-per-row decproj.

typedef __bf16 bf16x8 __attribute__((ext_vector_type(8)));
typedef __bf16 bf16x2 __attribute__((ext_vector_type(2)));
typedef float floatx4 __attribute__((ext_vector_type(4)));

#define M_TOT 65536
#define D_DIM 1024
#define WA_LD 2048
#define S_DIM 2048

__device__ __forceinline__ unsigned int pack2(float a, float b) {
#if __has_builtin(__builtin_amdgcn_cvt_pk_bf16_f32)
    bf16x2 p = __builtin_amdgcn_cvt_pk_bf16_f32(a, b);
    return __builtin_bit_cast(unsigned int, p);
#else
    unsigned int ua = __float_as_uint(a), ub = __float_as_uint(b);
    ua += 0x7fffu + ((ua >> 16) & 1u);     // RNE (inputs finite)
    ub += 0x7fffu + ((ub >> 16) & 1u);
    return __builtin_amdgcn_perm(ub, ua, 0x07060302);  // {ub.hi16, ua.hi16}
#endif
}

// ---------------- kernel 1: dec_proj[b][e] = sum_k dec[b,k] * W_a[e,k] ----------------
// grid (256, 32) block 256: one wave per e (4 e per block), fully coalesced Wd reads.
__global__ __launch_bounds__(256) void decproj_kernel(
    const float* __restrict__ dec,
    const float* __restrict__ Wa,
    float* __restrict__ dp)
{
    const int b    = blockIdx.y;
    const int wave = threadIdx.x >> 6;
    const int lane = threadIdx.x & 63;
    const int e    = blockIdx.x * 4 + wave;

    __shared__ float s_d[1024];
    for (int t = threadIdx.x; t < 1024; t += 256)
        s_d[t] = dec[b * 1024 + t];
    __syncthreads();

    const float* wrow = Wa + (size_t)e * WA_LD;   // Wd = W_a[:, :1024]
    float sum = 0.f;
    #pragma unroll
    for (int k0 = 0; k0 < 1024; k0 += 256) {
        float4 w = *(const float4*)(wrow + k0 + lane * 4);
        float4 d = *(const float4*)(&s_d[k0 + lane * 4]);
        sum += w.x * d.x + w.y * d.y + w.z * d.z + w.w * d.w;
    }
    #pragma unroll
    for (int msk = 1; msk < 64; msk <<= 1)
        sum += __shfl_xor(sum, msk, 64);
    if (lane == 0)
        dp[b * 1024 + e] = sum;
}

// ---------------- kernel 2: fused GEMM (enc @ We^T) + tanh + v-dot -> partial scores ----
// grid (8, 512) block 256. Tile BM=128 BN=128 BK=32. fp32 loads -> HW pack -> bf16 LDS.
__global__ __launch_bounds__(256) void fused_gemm_kernel(
    const float* __restrict__ enc,    // [65536,1024]
    const float* __restrict__ Wa,     // [1024,2048]
    const float* __restrict__ v,      // [1024]
    const float* __restrict__ dp,     // [32,1024]
    float* __restrict__ partial)      // [8][65536]
{
    __shared__ unsigned short As[128 * 32];
    __shared__ unsigned short Bs[128 * 32];
    __shared__ float s_dec[128];
    __shared__ float s_v[128];
    __shared__ float s_score[128];

    const int tid  = threadIdx.x;
    const int lane = tid & 63;
    const int wave = tid >> 6;
    const int wm   = wave >> 1;   // 0..1
    const int wn   = wave & 1;    // 0..1

    // XCD swizzle: 8 n-blocks sharing one A-tile keep flat%8 fixed -> same XCD L2.
    const int flat    = blockIdx.y * 8 + blockIdx.x;
    const int n_block = (flat >> 3) & 7;
    const int m_block = (flat & 7) | ((flat >> 6) << 3);
    const int b_idx   = m_block >> 4;            // 2048/128 = 16 m-tiles per batch row

    if (tid < 128) {
        s_dec[tid] = dp[b_idx * 1024 + n_block * 128 + tid];
        s_v[tid]   = v[n_block * 128 + tid];
    }

    const int r0  = tid >> 2;          // rows r0 and r0+64
    const int kk  = (tid & 3) * 8;     // k-offset (elements) within 32-wide tile
    const int r16 = lane & 15;
    const int q   = lane >> 4;

    const float* A_base = enc + (size_t)m_block * 128 * D_DIM;
    const float* B_base = Wa + (size_t)n_block * 128 * WA_LD + D_DIM;  // We = W_a[:,1024:]

    floatx4 acc[4][4] = {};

    for (int k0 = 0; k0 < 1024; k0 += 32) {
        float4 a0l = *(const float4*)(A_base + (size_t)r0        * D_DIM + k0 + kk);
        float4 a0h = *(const float4*)(A_base + (size_t)r0        * D_DIM + k0 + kk + 4);
        float4 a1l = *(const float4*)(A_base + (size_t)(r0 + 64) * D_DIM + k0 + kk);
        float4 a1h = *(const float4*)(A_base + (size_t)(r0 + 64) * D_DIM + k0 + kk + 4);
        float4 b0l = *(const float4*)(B_base + (size_t)r0        * WA_LD + k0 + kk);
        float4 b0h = *(const float4*)(B_base + (size_t)r0        * WA_LD + k0 + kk + 4);
        float4 b1l = *(const float4*)(B_base + (size_t)(r0 + 64) * WA_LD + k0 + kk);
        float4 b1h = *(const float4*)(B_base + (size_t)(r0 + 64) * WA_LD + k0 + kk + 4);
        uint4 pa0 = { pack2(a0l.x, a0l.y), pack2(a0l.z, a0l.w), pack2(a0h.x, a0h.y), pack2(a0h.z, a0h.w) };
        uint4 pa1 = { pack2(a1l.x, a1l.y), pack2(a1l.z, a1l.w), pack2(a1h.x, a1h.y), pack2(a1h.z, a1h.w) };
        uint4 pb0 = { pack2(b0l.x, b0l.y), pack2(b0l.z, b0l.w), pack2(b0h.x, b0h.y), pack2(b0h.z, b0h.w) };
        uint4 pb1 = { pack2(b1l.x, b1l.y), pack2(b1l.z, b1l.w), pack2(b1h.x, b1h.y), pack2(b1h.z, b1h.w) };
        __syncthreads();   // all waves done reading LDS from previous iteration
        *(uint4*)&As[r0        * 32 + kk] = pa0;
        *(uint4*)&As[(r0 + 64) * 32 + kk] = pa1;
        *(uint4*)&Bs[r0        * 32 + kk] = pb0;
        *(uint4*)&Bs[(r0 + 64) * 32 + kk] = pb1;
        __syncthreads();   // tile visible

        bf16x8 af[4], bfr[4];
        #pragma unroll
        for (int i = 0; i < 4; ++i)
            af[i] = *(const bf16x8*)&As[(wm * 64 + i * 16 + r16) * 32 + q * 8];
        #pragma unroll
        for (int j = 0; j < 4; ++j)
            bfr[j] = *(const bf16x8*)&Bs[(wn * 64 + j * 16 + r16) * 32 + q * 8];
        #pragma unroll
        for (int i = 0; i < 4; ++i)
            #pragma unroll
            for (int j = 0; j < 4; ++j)
                acc[i][j] = __builtin_amdgcn_mfma_f32_16x16x32_bf16(af[i], bfr[j], acc[i][j], 0, 0, 0);
    }

    // ---- epilogue: h = tanh(acc + dec), p[m] += h * v[n]; reduce over n ----
    float p[4][4] = {};
    #pragma unroll
    for (int j = 0; j < 4; ++j) {
        const int nl = wn * 64 + j * 16 + r16;    // C/D: col = lane&15 -> n
        const float dd = s_dec[nl];
        const float vv = s_v[nl];
        #pragma unroll
        for (int i = 0; i < 4; ++i) {
            #pragma unroll
            for (int r = 0; r < 4; ++r) {         // C/D: row = q*4+r -> m
                float x = acc[i][j][r] + dd;
                if (!(x > -8.f)) x = -8.f;        // NaN-proof clamp
                if (x > 8.f)     x = 8.f;
                float e2 = __expf(2.f * x);
                float h  = 1.f - 2.f * __builtin_amdgcn_rcpf(e2 + 1.f);
                p[i][r] += h * vv;
            }
        }
    }
    #pragma unroll
    for (int msk = 1; msk < 16; msk <<= 1) {
        #pragma unroll
        for (int i = 0; i < 4; ++i)
            #pragma unroll
            for (int r = 0; r < 4; ++r)
                p[i][r] += __shfl_xor(p[i][r], msk, 64);
    }
    __syncthreads();
    if (wn == 0 && r16 == 0) {
        #pragma unroll
        for (int i = 0; i < 4; ++i)
            #pragma unroll
            for (int r = 0; r < 4; ++r)
                s_score[wm * 64 + i * 16 + q * 4 + r] = p[i][r];
    }
    __syncthreads();
    if (wn == 1 && r16 == 0) {
        #pragma unroll
        for (int i = 0; i < 4; ++i)
            #pragma unroll
            for (int r = 0; r < 4; ++r)
                s_score[wm * 64 + i * 16 + q * 4 + r] += p[i][r];
    }
    __syncthreads();
    if (tid < 128)
        partial[(size_t)n_block * M_TOT + m_block * 128 + tid] = s_score[tid];
}

// ---------------- kernel 3: softmax over s per batch row ----------------
__global__ __launch_bounds__(256) void softmax_kernel(
    const float* __restrict__ partial,   // [8][65536]
    float* __restrict__ out)             // [32][2048] f32
{
    const int b = blockIdx.x;
    const int tid = threadIdx.x;
    __shared__ float wmax[4], wsum[4];

    float sc[8];
    float mx = -1e30f;
    #pragma unroll
    for (int ii = 0; ii < 8; ++ii) {
        const int s = tid + ii * 256;
        float sum = 0.f;
        #pragma unroll
        for (int pp = 0; pp < 8; ++pp)
            sum += partial[(size_t)pp * M_TOT + b * S_DIM + s];
        sc[ii] = sum;
        mx = fmaxf(mx, sum);
    }
    #pragma unroll
    for (int msk = 1; msk < 64; msk <<= 1) mx = fmaxf(mx, __shfl_xor(mx, msk, 64));
    if ((tid & 63) == 0) wmax[tid >> 6] = mx;
    __syncthreads();
    mx = fmaxf(fmaxf(wmax[0], wmax[1]), fmaxf(wmax[2], wmax[3]));

    float ex[8];
    float tot = 0.f;
    #pragma unroll
    for (int ii = 0; ii < 8; ++ii) { ex[ii] = __expf(sc[ii] - mx); tot += ex[ii]; }
    #pragma unroll
    for (int msk = 1; msk < 64; msk <<= 1) tot += __shfl_xor(tot, msk, 64);
    if ((tid & 63) == 0) wsum[tid >> 6] = tot;
    __syncthreads();
    tot = wsum[0] + wsum[1] + wsum[2] + wsum[3];
    const float inv = 1.f / tot;
    #pragma unroll
    for (int ii = 0; ii < 8; ++ii)
        out[b * S_DIM + tid + ii * 256] = ex[ii] * inv;
}

extern "C" void kernel_launch(void* const* d_in, const int* in_sizes, int n_in,
                              void* d_out, int out_size, void* d_ws, size_t ws_size,
                              hipStream_t stream) {
    (void)in_sizes; (void)n_in; (void)out_size; (void)ws_size;
    const float* dec = (const float*)d_in[0];
    const float* enc = (const float*)d_in[1];
    const float* Wa  = (const float*)d_in[2];
    const float* v   = (const float*)d_in[3];
    float* out = (float*)d_out;

    float* dp      = (float*)d_ws;        // 32*1024 floats   = 128 KB
    float* partial = dp + 32 * 1024;      // 8*65536 floats   = 2 MB

    decproj_kernel<<<dim3(256, 32), 256, 0, stream>>>(dec, Wa, dp);
    fused_gemm_kernel<<<dim3(8, 512), 256, 0, stream>>>(enc, Wa, v, dp, partial);
    softmax_kernel<<<32, 256, 0, stream>>>(partial, out);
}